// Round 1
// baseline (280.204 us; speedup 1.0000x reference)
//
#include <hip/hip_runtime.h>

// RoIAlign forward, Detectron-style (no aligned offset), sampling_ratio = 2.
// features: [N=2, C=256, H=200, W=200] fp32
// rois:     [num_rois, 5] fp32 (batch_idx, x1, y1, x2, y2) in image space
// out:      [num_rois, C, 7, 7] fp32
//
// Mapping: 1 thread per output element, flat index ((roi*C + c)*49 + s),
// s = ph*7+pw. Consecutive lanes iterate spatial cells within one channel
// plane -> gathers cluster in a small patch (good L1/L2 locality), stores
// are fully coalesced.

#define POOLED_H 7
#define POOLED_W 7
#define SPATIAL_SCALE 0.0625f
#define FEAT_C 256
#define FEAT_H 200
#define FEAT_W 200

__device__ __forceinline__ float bilinear_tap(const float* __restrict__ plane,
                                              float y, float x) {
    const int H = FEAT_H, W = FEAT_W;
    // validity window per reference: (-1, H) x (-1, W)
    if (!(y > -1.0f && y < (float)H && x > -1.0f && x < (float)W)) return 0.0f;
    y = fmaxf(y, 0.0f);
    x = fmaxf(x, 0.0f);
    int y0 = min((int)floorf(y), H - 1);
    int x0 = min((int)floorf(x), W - 1);
    int y1 = min(y0 + 1, H - 1);
    int x1 = min(x0 + 1, W - 1);
    // snap coordinate when at/past the last row/col (matches reference)
    if (y0 >= H - 1) y = (float)y0;
    if (x0 >= W - 1) x = (float)x0;
    float ly = y - (float)y0;
    float lx = x - (float)x0;
    float hy = 1.0f - ly;
    float hx = 1.0f - lx;
    float v00 = plane[y0 * W + x0];
    float v01 = plane[y0 * W + x1];
    float v10 = plane[y1 * W + x0];
    float v11 = plane[y1 * W + x1];
    return hy * (hx * v00 + lx * v01) + ly * (hx * v10 + lx * v11);
}

__global__ __launch_bounds__(256) void roialign_kernel(
    const float* __restrict__ features,
    const float* __restrict__ rois,
    float* __restrict__ out,
    int num_rois) {
    const int C = FEAT_C, H = FEAT_H, W = FEAT_W;
    int i = blockIdx.x * blockDim.x + threadIdx.x;
    int total = num_rois * C * POOLED_H * POOLED_W;
    if (i >= total) return;

    int s = i % (POOLED_H * POOLED_W);
    int t = i / (POOLED_H * POOLED_W);
    int c = t % C;
    int roi = t / C;
    int ph = s / POOLED_W;
    int pw = s % POOLED_W;

    const float* r = rois + roi * 5;
    int b = (int)r[0];
    float x1 = r[1] * SPATIAL_SCALE;
    float y1 = r[2] * SPATIAL_SCALE;
    float x2 = r[3] * SPATIAL_SCALE;
    float y2 = r[4] * SPATIAL_SCALE;
    float roi_w = fmaxf(x2 - x1, 1.0f);
    float roi_h = fmaxf(y2 - y1, 1.0f);
    float bin_w = roi_w * (1.0f / POOLED_W);
    float bin_h = roi_h * (1.0f / POOLED_H);

    const float* plane = features + ((size_t)(b * C + c)) * (H * W);

    // fixed 2x2 sample grid inside the bin (sampling_ratio = 2)
    float ybase = y1 + (float)ph * bin_h;
    float xbase = x1 + (float)pw * bin_w;
    float acc = 0.0f;
#pragma unroll
    for (int iy = 0; iy < 2; ++iy) {
        float yy = ybase + ((float)iy + 0.5f) * bin_h * 0.5f;
#pragma unroll
        for (int ix = 0; ix < 2; ++ix) {
            float xx = xbase + ((float)ix + 0.5f) * bin_w * 0.5f;
            acc += bilinear_tap(plane, yy, xx);
        }
    }
    out[i] = acc * 0.25f;
}

extern "C" void kernel_launch(void* const* d_in, const int* in_sizes, int n_in,
                              void* d_out, int out_size, void* d_ws, size_t ws_size,
                              hipStream_t stream) {
    const float* features = (const float*)d_in[0];
    const float* rois = (const float*)d_in[1];
    float* out = (float*)d_out;
    int num_rois = in_sizes[1] / 5;
    int total = num_rois * FEAT_C * POOLED_H * POOLED_W;
    int block = 256;
    int grid = (total + block - 1) / block;
    roialign_kernel<<<grid, block, 0, stream>>>(features, rois, out, num_rois);
}